// Round 1
// baseline (1912.747 us; speedup 1.0000x reference)
//
#include <hip/hip_runtime.h>
#include <hip/hip_bf16.h>

#define LRELU_SLOPE 0.01f

// ---------------------------------------------------------------------------
// CSR build kernels
// ---------------------------------------------------------------------------
__global__ void count_kernel(const int* __restrict__ dst, int* __restrict__ counts, int E) {
    int e = blockIdx.x * blockDim.x + threadIdx.x;
    if (e < E) atomicAdd(&counts[dst[e]], 1);
}

// exclusive scan of counts[0..n) -> row_ptr[0..n], row_ptr[n] = total. single block.
__global__ void scan_kernel(const int* __restrict__ counts, int* __restrict__ row_ptr, int n) {
    __shared__ int s[1024];
    __shared__ int s_running;
    const int t = threadIdx.x;
    if (t == 0) s_running = 0;
    __syncthreads();
    for (int base = 0; base < n; base += 1024) {
        int c = (base + t < n) ? counts[base + t] : 0;
        s[t] = c;
        __syncthreads();
        // Hillis-Steele inclusive scan
        for (int off = 1; off < 1024; off <<= 1) {
            int v = (t >= off) ? s[t - off] : 0;
            __syncthreads();
            s[t] += v;
            __syncthreads();
        }
        int incl = s[t];
        int run = s_running;
        if (base + t < n) row_ptr[base + t] = run + incl - c;
        __syncthreads();
        if (t == 1023) s_running = run + incl;
        __syncthreads();
    }
    if (t == 0) row_ptr[n] = s_running;
}

__global__ void fill_kernel(const int* __restrict__ src, const int* __restrict__ dst,
                            const float* __restrict__ attn,
                            const int* __restrict__ row_ptr, int* __restrict__ counts,
                            int* __restrict__ csr_src, float* __restrict__ csr_attn, int E) {
    int e = blockIdx.x * blockDim.x + threadIdx.x;
    if (e < E) {
        int d = dst[e];
        int pos = row_ptr[d] + atomicAdd(&counts[d], 1);
        csr_src[pos] = src[e];
        csr_attn[pos] = attn[e];
    }
}

// ---------------------------------------------------------------------------
// copy x into out[:, 0:128]  (out row stride = 352 floats = 88 float4)
// ---------------------------------------------------------------------------
__global__ void copy_x_kernel(const float4* __restrict__ x, float4* __restrict__ out, int n4) {
    int i = blockIdx.x * blockDim.x + threadIdx.x;
    if (i < n4) {
        int v = i >> 5;          // 32 float4 per row
        int c = i & 31;
        out[(long)v * 88 + c] = x[i];
    }
}

// ---------------------------------------------------------------------------
// aggregation: one wave per node, lanes span D. h[v] = sum_e attn_e * x[src_e]
// ---------------------------------------------------------------------------
template <int D>
__global__ void agg_kernel(const float* __restrict__ xin, long xstride,
                           const int* __restrict__ row_ptr,
                           const int* __restrict__ csr_src,
                           const float* __restrict__ csr_attn,
                           float* __restrict__ hagg, int n_nodes) {
    const int lane = threadIdx.x & 63;
    const int wid = (blockIdx.x * blockDim.x + threadIdx.x) >> 6;
    if (wid >= n_nodes) return;
    const int e0 = row_ptr[wid], e1 = row_ptr[wid + 1];
    if (D == 128) {
        float2 acc = {0.f, 0.f};
        for (int e = e0; e < e1; ++e) {
            int s = csr_src[e];
            float a = csr_attn[e];
            const float2* r = reinterpret_cast<const float2*>(xin + (long)s * xstride);
            float2 xv = r[lane];
            acc.x = fmaf(a, xv.x, acc.x);
            acc.y = fmaf(a, xv.y, acc.y);
        }
        reinterpret_cast<float2*>(hagg + (long)wid * 128)[lane] = acc;
    } else {  // D == 64
        float acc = 0.f;
        for (int e = e0; e < e1; ++e) {
            int s = csr_src[e];
            float a = csr_attn[e];
            acc = fmaf(a, xin[(long)s * xstride + lane], acc);
        }
        hagg[(long)wid * 64 + lane] = acc;
    }
}

// ---------------------------------------------------------------------------
// bi-interaction MLP: out[v,o] = lrelu((x+h)@W1+b1) + lrelu((x*h)@W2+b2)
// block = 256 threads = (256/OUT) node-slots x OUT outputs; NT nodes per slot.
// ---------------------------------------------------------------------------
template <int IN, int OUT, int NT>
__global__ void mlp_kernel(const float* __restrict__ xin, long xstride,
                           const float* __restrict__ hagg,
                           const float* __restrict__ W1, const float* __restrict__ b1,
                           const float* __restrict__ W2, const float* __restrict__ b2,
                           float* __restrict__ out, long ostride, int n_nodes) {
    constexpr int SLOTS = 256 / OUT;
    constexpr int NPB = SLOTS * NT;
    __shared__ float s_xp[NPB][IN + 1];
    __shared__ float s_xm[NPB][IN + 1];
    const int t = threadIdx.x;
    const int o = t % OUT;
    const int slot = t / OUT;
    const int node0 = blockIdx.x * NPB;

    for (int idx = t; idx < NPB * IN; idx += 256) {
        int n = idx / IN, k = idx % IN;
        int v = node0 + n;
        float xv = 0.f, hv = 0.f;
        if (v < n_nodes) {
            xv = xin[(long)v * xstride + k];
            hv = hagg[(long)v * IN + k];
        }
        s_xp[n][k] = xv + hv;
        s_xm[n][k] = xv * hv;
    }
    __syncthreads();

    float acc1[NT], acc2[NT];
#pragma unroll
    for (int j = 0; j < NT; ++j) { acc1[j] = 0.f; acc2[j] = 0.f; }

    for (int k = 0; k < IN; ++k) {
        float w1 = W1[k * OUT + o];
        float w2 = W2[k * OUT + o];
#pragma unroll
        for (int j = 0; j < NT; ++j) {
            int n = slot * NT + j;
            acc1[j] = fmaf(s_xp[n][k], w1, acc1[j]);
            acc2[j] = fmaf(s_xm[n][k], w2, acc2[j]);
        }
    }

    const float bb1 = b1[o], bb2 = b2[o];
#pragma unroll
    for (int j = 0; j < NT; ++j) {
        int v = node0 + slot * NT + j;
        if (v < n_nodes) {
            float r1 = acc1[j] + bb1;
            float r2 = acc2[j] + bb2;
            r1 = r1 >= 0.f ? r1 : LRELU_SLOPE * r1;
            r2 = r2 >= 0.f ? r2 : LRELU_SLOPE * r2;
            out[(long)v * ostride + o] = r1 + r2;
        }
    }
}

// ---------------------------------------------------------------------------
extern "C" void kernel_launch(void* const* d_in, const int* in_sizes, int n_in,
                              void* d_out, int out_size, void* d_ws, size_t ws_size,
                              hipStream_t stream) {
    const float* x    = (const float*)d_in[0];
    const int*   src  = (const int*)d_in[1];
    const int*   dst  = (const int*)d_in[2];
    const float* attn = (const float*)d_in[3];
    const float* W1_0 = (const float*)d_in[4];
    const float* b1_0 = (const float*)d_in[5];
    const float* W2_0 = (const float*)d_in[6];
    const float* b2_0 = (const float*)d_in[7];
    const float* W1_1 = (const float*)d_in[8];
    const float* b1_1 = (const float*)d_in[9];
    const float* W2_1 = (const float*)d_in[10];
    const float* b2_1 = (const float*)d_in[11];
    const float* W1_2 = (const float*)d_in[12];
    const float* b1_2 = (const float*)d_in[13];
    const float* W2_2 = (const float*)d_in[14];
    const float* b2_2 = (const float*)d_in[15];
    float* out = (float*)d_out;

    const int N = in_sizes[0] / 128;
    const int E = in_sizes[1];

    char* w = (char*)d_ws;
    size_t off = 0;
    auto alloc = [&](size_t bytes) -> void* {
        void* p = w + off;
        off += (bytes + 511) & ~(size_t)511;
        return p;
    };
    int*   counts   = (int*)alloc((size_t)N * 4);
    int*   row_ptr  = (int*)alloc((size_t)(N + 1) * 4);
    int*   csr_src  = (int*)alloc((size_t)E * 4);
    float* csr_attn = (float*)alloc((size_t)E * 4);
    float* h_agg    = (float*)alloc((size_t)N * 128 * 4);

    // ---- CSR build (reused by all 3 layers) ----
    hipMemsetAsync(counts, 0, (size_t)N * 4, stream);
    count_kernel<<<(E + 255) / 256, 256, 0, stream>>>(dst, counts, E);
    scan_kernel<<<1, 1024, 0, stream>>>(counts, row_ptr, N);
    hipMemsetAsync(counts, 0, (size_t)N * 4, stream);
    fill_kernel<<<(E + 255) / 256, 256, 0, stream>>>(src, dst, attn, row_ptr, counts,
                                                     csr_src, csr_attn, E);

    // ---- out[:, 0:128] = x ----
    copy_x_kernel<<<(N * 32 + 255) / 256, 256, 0, stream>>>((const float4*)x, (float4*)out, N * 32);

    // ---- layer 0: IN=128 OUT=128, input x (stride 128) -> out cols [128,256) ----
    agg_kernel<128><<<(N + 3) / 4, 256, 0, stream>>>(x, 128, row_ptr, csr_src, csr_attn, h_agg, N);
    mlp_kernel<128, 128, 4><<<(N + 7) / 8, 256, 0, stream>>>(x, 128, h_agg,
                                                             W1_0, b1_0, W2_0, b2_0,
                                                             out + 128, 352, N);

    // ---- layer 1: IN=128 OUT=64, input out cols [128,256) -> out cols [256,320) ----
    agg_kernel<128><<<(N + 3) / 4, 256, 0, stream>>>(out + 128, 352, row_ptr, csr_src, csr_attn, h_agg, N);
    mlp_kernel<128, 64, 4><<<(N + 15) / 16, 256, 0, stream>>>(out + 128, 352, h_agg,
                                                              W1_1, b1_1, W2_1, b2_1,
                                                              out + 256, 352, N);

    // ---- layer 2: IN=64 OUT=32, input out cols [256,320) -> out cols [320,352) ----
    agg_kernel<64><<<(N + 3) / 4, 256, 0, stream>>>(out + 256, 352, row_ptr, csr_src, csr_attn, h_agg, N);
    mlp_kernel<64, 32, 4><<<(N + 31) / 32, 256, 0, stream>>>(out + 256, 352, h_agg,
                                                             W1_2, b1_2, W2_2, b2_2,
                                                             out + 320, 352, N);
}

// Round 2
// 1345.971 us; speedup vs baseline: 1.4211x; 1.4211x over previous
//
#include <hip/hip_runtime.h>
#include <hip/hip_bf16.h>

#define LRELU_SLOPE 0.01f

// ---------------------------------------------------------------------------
// CSR build kernels
// ---------------------------------------------------------------------------
__global__ void count_kernel(const int* __restrict__ dst, int* __restrict__ counts, int E) {
    int e = blockIdx.x * blockDim.x + threadIdx.x;
    if (e < E) atomicAdd(&counts[dst[e]], 1);
}

// hierarchical exclusive scan, phase 1: per-block (1024) scan, write partial sums
__global__ void scan_blocks_kernel(const int* __restrict__ counts, int* __restrict__ row_ptr,
                                   int* __restrict__ partials, int n) {
    __shared__ int s[1024];
    const int t = threadIdx.x;
    const int i = blockIdx.x * 1024 + t;
    int c = (i < n) ? counts[i] : 0;
    s[t] = c;
    __syncthreads();
    for (int off = 1; off < 1024; off <<= 1) {
        int v = (t >= off) ? s[t - off] : 0;
        __syncthreads();
        s[t] += v;
        __syncthreads();
    }
    if (i < n) row_ptr[i] = s[t] - c;            // block-local exclusive
    if (t == 1023) partials[blockIdx.x] = s[1023];
}

// phase 2: single block scans the (<=1024) partials in-place (exclusive), writes total
__global__ void scan_partials_kernel(int* __restrict__ partials, int* __restrict__ row_ptr,
                                     int G, int n) {
    __shared__ int s[1024];
    const int t = threadIdx.x;
    int c = (t < G) ? partials[t] : 0;
    s[t] = c;
    __syncthreads();
    for (int off = 1; off < 1024; off <<= 1) {
        int v = (t >= off) ? s[t - off] : 0;
        __syncthreads();
        s[t] += v;
        __syncthreads();
    }
    if (t < G) partials[t] = s[t] - c;           // exclusive
    if (t == 1023) row_ptr[n] = s[1023];         // grand total
}

// phase 3: add block offsets
__global__ void scan_add_kernel(int* __restrict__ row_ptr, const int* __restrict__ partials, int n) {
    int i = blockIdx.x * blockDim.x + threadIdx.x;
    if (i < n) row_ptr[i] += partials[i >> 10];
}

__global__ void fill_kernel(const int* __restrict__ src, const int* __restrict__ dst,
                            const float* __restrict__ attn,
                            const int* __restrict__ row_ptr, int* __restrict__ counts,
                            int2* __restrict__ csr_edge, int E) {
    int e = blockIdx.x * blockDim.x + threadIdx.x;
    if (e < E) {
        int d = dst[e];
        int pos = row_ptr[d] + atomicAdd(&counts[d], 1);
        csr_edge[pos] = make_int2(src[e], __float_as_int(attn[e]));
    }
}

// ---------------------------------------------------------------------------
// copy x into out[:, 0:128]  (out row stride = 352 floats = 88 float4)
// ---------------------------------------------------------------------------
__global__ void copy_x_kernel(const float4* __restrict__ x, float4* __restrict__ out, int n4) {
    int i = blockIdx.x * blockDim.x + threadIdx.x;
    if (i < n4) {
        int v = i >> 5;          // 32 float4 per row
        int c = i & 31;
        out[(long)v * 88 + c] = x[i];
    }
}

// ---------------------------------------------------------------------------
// aggregation: one wave per node, lanes span D. h[v] = sum_e attn_e * x[src_e]
// unrolled x4: 4 independent row gathers in flight per wave.
// ---------------------------------------------------------------------------
template <int D>
__global__ void agg_kernel(const float* __restrict__ xin, long xstride,
                           const int* __restrict__ row_ptr,
                           const int2* __restrict__ csr_edge,
                           float* __restrict__ hagg, int n_nodes) {
    const int lane = threadIdx.x & 63;
    const int wid = (blockIdx.x * blockDim.x + threadIdx.x) >> 6;
    if (wid >= n_nodes) return;
    const int e0 = row_ptr[wid], e1 = row_ptr[wid + 1];
    if (D == 128) {
        float2 accA = {0.f, 0.f}, accB = {0.f, 0.f};
        int e = e0;
        for (; e + 4 <= e1; e += 4) {
            int2 p0 = csr_edge[e + 0];
            int2 p1 = csr_edge[e + 1];
            int2 p2 = csr_edge[e + 2];
            int2 p3 = csr_edge[e + 3];
            float2 x0 = reinterpret_cast<const float2*>(xin + (long)p0.x * xstride)[lane];
            float2 x1 = reinterpret_cast<const float2*>(xin + (long)p1.x * xstride)[lane];
            float2 x2 = reinterpret_cast<const float2*>(xin + (long)p2.x * xstride)[lane];
            float2 x3 = reinterpret_cast<const float2*>(xin + (long)p3.x * xstride)[lane];
            float a0 = __int_as_float(p0.y), a1 = __int_as_float(p1.y);
            float a2 = __int_as_float(p2.y), a3 = __int_as_float(p3.y);
            accA.x = fmaf(a0, x0.x, accA.x); accA.y = fmaf(a0, x0.y, accA.y);
            accB.x = fmaf(a1, x1.x, accB.x); accB.y = fmaf(a1, x1.y, accB.y);
            accA.x = fmaf(a2, x2.x, accA.x); accA.y = fmaf(a2, x2.y, accA.y);
            accB.x = fmaf(a3, x3.x, accB.x); accB.y = fmaf(a3, x3.y, accB.y);
        }
        for (; e < e1; ++e) {
            int2 p = csr_edge[e];
            float2 xv = reinterpret_cast<const float2*>(xin + (long)p.x * xstride)[lane];
            float a = __int_as_float(p.y);
            accA.x = fmaf(a, xv.x, accA.x); accA.y = fmaf(a, xv.y, accA.y);
        }
        accA.x += accB.x; accA.y += accB.y;
        reinterpret_cast<float2*>(hagg + (long)wid * 128)[lane] = accA;
    } else {  // D == 64
        float accA = 0.f, accB = 0.f;
        int e = e0;
        for (; e + 4 <= e1; e += 4) {
            int2 p0 = csr_edge[e + 0];
            int2 p1 = csr_edge[e + 1];
            int2 p2 = csr_edge[e + 2];
            int2 p3 = csr_edge[e + 3];
            float x0 = xin[(long)p0.x * xstride + lane];
            float x1 = xin[(long)p1.x * xstride + lane];
            float x2 = xin[(long)p2.x * xstride + lane];
            float x3 = xin[(long)p3.x * xstride + lane];
            accA = fmaf(__int_as_float(p0.y), x0, accA);
            accB = fmaf(__int_as_float(p1.y), x1, accB);
            accA = fmaf(__int_as_float(p2.y), x2, accA);
            accB = fmaf(__int_as_float(p3.y), x3, accB);
        }
        for (; e < e1; ++e) {
            int2 p = csr_edge[e];
            accA = fmaf(__int_as_float(p.y), xin[(long)p.x * xstride + lane], accA);
        }
        hagg[(long)wid * 64 + lane] = accA + accB;
    }
}

// ---------------------------------------------------------------------------
// bi-interaction MLP: out[v,o] = lrelu((x+h)@W1+b1) + lrelu((x*h)@W2+b2)
// block = 256 threads = (256/OUT) node-slots x OUT outputs; NT nodes per slot.
// ---------------------------------------------------------------------------
template <int IN, int OUT, int NT>
__global__ void mlp_kernel(const float* __restrict__ xin, long xstride,
                           const float* __restrict__ hagg,
                           const float* __restrict__ W1, const float* __restrict__ b1,
                           const float* __restrict__ W2, const float* __restrict__ b2,
                           float* __restrict__ out, long ostride, int n_nodes) {
    constexpr int SLOTS = 256 / OUT;
    constexpr int NPB = SLOTS * NT;
    __shared__ float s_xp[NPB][IN + 1];
    __shared__ float s_xm[NPB][IN + 1];
    const int t = threadIdx.x;
    const int o = t % OUT;
    const int slot = t / OUT;
    const int node0 = blockIdx.x * NPB;

    for (int idx = t; idx < NPB * IN; idx += 256) {
        int n = idx / IN, k = idx % IN;
        int v = node0 + n;
        float xv = 0.f, hv = 0.f;
        if (v < n_nodes) {
            xv = xin[(long)v * xstride + k];
            hv = hagg[(long)v * IN + k];
        }
        s_xp[n][k] = xv + hv;
        s_xm[n][k] = xv * hv;
    }
    __syncthreads();

    float acc1[NT], acc2[NT];
#pragma unroll
    for (int j = 0; j < NT; ++j) { acc1[j] = 0.f; acc2[j] = 0.f; }

    for (int k = 0; k < IN; ++k) {
        float w1 = W1[k * OUT + o];
        float w2 = W2[k * OUT + o];
#pragma unroll
        for (int j = 0; j < NT; ++j) {
            int n = slot * NT + j;
            acc1[j] = fmaf(s_xp[n][k], w1, acc1[j]);
            acc2[j] = fmaf(s_xm[n][k], w2, acc2[j]);
        }
    }

    const float bb1 = b1[o], bb2 = b2[o];
#pragma unroll
    for (int j = 0; j < NT; ++j) {
        int v = node0 + slot * NT + j;
        if (v < n_nodes) {
            float r1 = acc1[j] + bb1;
            float r2 = acc2[j] + bb2;
            r1 = r1 >= 0.f ? r1 : LRELU_SLOPE * r1;
            r2 = r2 >= 0.f ? r2 : LRELU_SLOPE * r2;
            out[(long)v * ostride + o] = r1 + r2;
        }
    }
}

// ---------------------------------------------------------------------------
extern "C" void kernel_launch(void* const* d_in, const int* in_sizes, int n_in,
                              void* d_out, int out_size, void* d_ws, size_t ws_size,
                              hipStream_t stream) {
    const float* x    = (const float*)d_in[0];
    const int*   src  = (const int*)d_in[1];
    const int*   dst  = (const int*)d_in[2];
    const float* attn = (const float*)d_in[3];
    const float* W1_0 = (const float*)d_in[4];
    const float* b1_0 = (const float*)d_in[5];
    const float* W2_0 = (const float*)d_in[6];
    const float* b2_0 = (const float*)d_in[7];
    const float* W1_1 = (const float*)d_in[8];
    const float* b1_1 = (const float*)d_in[9];
    const float* W2_1 = (const float*)d_in[10];
    const float* b2_1 = (const float*)d_in[11];
    const float* W1_2 = (const float*)d_in[12];
    const float* b1_2 = (const float*)d_in[13];
    const float* W2_2 = (const float*)d_in[14];
    const float* b2_2 = (const float*)d_in[15];
    float* out = (float*)d_out;

    const int N = in_sizes[0] / 128;
    const int E = in_sizes[1];

    char* w = (char*)d_ws;
    size_t off = 0;
    auto alloc = [&](size_t bytes) -> void* {
        void* p = w + off;
        off += (bytes + 511) & ~(size_t)511;
        return p;
    };
    int*   counts   = (int*)alloc((size_t)N * 4);
    int*   row_ptr  = (int*)alloc((size_t)(N + 1) * 4);
    int*   partials = (int*)alloc((size_t)1024 * 4);
    int2*  csr_edge = (int2*)alloc((size_t)E * 8);
    float* h_agg    = (float*)alloc((size_t)N * 128 * 4);

    const int G = (N + 1023) / 1024;   // scan blocks (98 for N=100000, <=1024 required)

    // ---- CSR build (reused by all 3 layers) ----
    hipMemsetAsync(counts, 0, (size_t)N * 4, stream);
    count_kernel<<<(E + 255) / 256, 256, 0, stream>>>(dst, counts, E);
    scan_blocks_kernel<<<G, 1024, 0, stream>>>(counts, row_ptr, partials, N);
    scan_partials_kernel<<<1, 1024, 0, stream>>>(partials, row_ptr, G, N);
    scan_add_kernel<<<(N + 255) / 256, 256, 0, stream>>>(row_ptr, partials, N);
    hipMemsetAsync(counts, 0, (size_t)N * 4, stream);
    fill_kernel<<<(E + 255) / 256, 256, 0, stream>>>(src, dst, attn, row_ptr, counts,
                                                     csr_edge, E);

    // ---- out[:, 0:128] = x ----
    copy_x_kernel<<<(N * 32 + 255) / 256, 256, 0, stream>>>((const float4*)x, (float4*)out, N * 32);

    // ---- layer 0: IN=128 OUT=128, input x (stride 128) -> out cols [128,256) ----
    agg_kernel<128><<<(N + 3) / 4, 256, 0, stream>>>(x, 128, row_ptr, csr_edge, h_agg, N);
    mlp_kernel<128, 128, 4><<<(N + 7) / 8, 256, 0, stream>>>(x, 128, h_agg,
                                                             W1_0, b1_0, W2_0, b2_0,
                                                             out + 128, 352, N);

    // ---- layer 1: IN=128 OUT=64, input out cols [128,256) -> out cols [256,320) ----
    agg_kernel<128><<<(N + 3) / 4, 256, 0, stream>>>(out + 128, 352, row_ptr, csr_edge, h_agg, N);
    mlp_kernel<128, 64, 4><<<(N + 15) / 16, 256, 0, stream>>>(out + 128, 352, h_agg,
                                                              W1_1, b1_1, W2_1, b2_1,
                                                              out + 256, 352, N);

    // ---- layer 2: IN=64 OUT=32, input out cols [256,320) -> out cols [320,352) ----
    agg_kernel<64><<<(N + 3) / 4, 256, 0, stream>>>(out + 256, 352, row_ptr, csr_edge, h_agg, N);
    mlp_kernel<64, 32, 4><<<(N + 31) / 32, 256, 0, stream>>>(out + 256, 352, h_agg,
                                                             W1_2, b1_2, W2_2, b2_2,
                                                             out + 320, 352, N);
}

// Round 4
// 1070.062 us; speedup vs baseline: 1.7875x; 1.2578x over previous
//
#include <hip/hip_runtime.h>
#include <hip/hip_bf16.h>

#define LRELU_SLOPE 0.01f

__device__ __forceinline__ unsigned int f2bf_rne(float f) {
    unsigned int u = __float_as_uint(f);
    u += 0x7FFFu + ((u >> 16) & 1u);
    return u >> 16;
}
__device__ __forceinline__ float bf_lo(unsigned int u) { return __uint_as_float(u << 16); }
__device__ __forceinline__ float bf_hi(unsigned int u) { return __uint_as_float(u & 0xFFFF0000u); }

// ---------------------------------------------------------------------------
// CSR build kernels
// ---------------------------------------------------------------------------
__global__ void count_kernel(const int* __restrict__ dst, int* __restrict__ counts, int E) {
    int e = blockIdx.x * blockDim.x + threadIdx.x;
    if (e < E) atomicAdd(&counts[dst[e]], 1);
}

// phase 1: per-block (1024) scan, write partial sums; also re-zero counts for fill
__global__ void scan_blocks_kernel(int* __restrict__ counts, int* __restrict__ row_ptr,
                                   int* __restrict__ partials, int n) {
    __shared__ int s[1024];
    const int t = threadIdx.x;
    const int i = blockIdx.x * 1024 + t;
    int c = (i < n) ? counts[i] : 0;
    s[t] = c;
    __syncthreads();
    for (int off = 1; off < 1024; off <<= 1) {
        int v = (t >= off) ? s[t - off] : 0;
        __syncthreads();
        s[t] += v;
        __syncthreads();
    }
    if (i < n) {
        row_ptr[i] = s[t] - c;            // block-local exclusive
        counts[i] = 0;                    // ready for fill cursors
    }
    if (t == 1023) partials[blockIdx.x] = s[1023];
}

// phase 2: single block scans the (<=1024) partials in-place (exclusive), writes total
__global__ void scan_partials_kernel(int* __restrict__ partials, int* __restrict__ row_ptr,
                                     int G, int n) {
    __shared__ int s[1024];
    const int t = threadIdx.x;
    int c = (t < G) ? partials[t] : 0;
    s[t] = c;
    __syncthreads();
    for (int off = 1; off < 1024; off <<= 1) {
        int v = (t >= off) ? s[t - off] : 0;
        __syncthreads();
        s[t] += v;
        __syncthreads();
    }
    if (t < G) partials[t] = s[t] - c;    // exclusive
    if (t == 1023) row_ptr[n] = s[1023];  // grand total
}

// phase 3: add block offsets
__global__ void scan_add_kernel(int* __restrict__ row_ptr, const int* __restrict__ partials, int n) {
    int i = blockIdx.x * blockDim.x + threadIdx.x;
    if (i < n) row_ptr[i] += partials[i >> 10];
}

__global__ void fill_kernel(const int* __restrict__ src, const int* __restrict__ dst,
                            const float* __restrict__ attn,
                            const int* __restrict__ row_ptr, int* __restrict__ counts,
                            int2* __restrict__ csr_edge, int E) {
    int e = blockIdx.x * blockDim.x + threadIdx.x;
    if (e < E) {
        int d = dst[e];
        int pos = row_ptr[d] + atomicAdd(&counts[d], 1);
        csr_edge[pos] = make_int2(src[e], __float_as_int(attn[e]));
    }
}

// ---------------------------------------------------------------------------
// copy x into out[:, 0:128]  (out row stride = 352 floats = 88 float4)
// ---------------------------------------------------------------------------
__global__ void copy_x_kernel(const float4* __restrict__ x, float4* __restrict__ out, int n4) {
    int i = blockIdx.x * blockDim.x + threadIdx.x;
    if (i < n4) {
        int v = i >> 5;
        int c = i & 31;
        out[(long)v * 88 + c] = x[i];
    }
}

// convert contiguous fp32 array to packed bf16 (uint = 2 bf16), n2 = count of float2
__global__ void cvt_kernel(const float2* __restrict__ xin, unsigned int* __restrict__ xb, int n2) {
    int i = blockIdx.x * blockDim.x + threadIdx.x;
    if (i < n2) {
        float2 v = xin[i];
        xb[i] = f2bf_rne(v.x) | (f2bf_rne(v.y) << 16);
    }
}

// ---------------------------------------------------------------------------
// aggregation D=128 (bf16 table): one wave per node, lane covers dims 2l,2l+1
// ---------------------------------------------------------------------------
__global__ void agg128_bf_kernel(const unsigned int* __restrict__ xb,   // row = 64 uints
                                 const int* __restrict__ row_ptr,
                                 const int2* __restrict__ csr_edge,
                                 float* __restrict__ hagg, int n_nodes) {
    const int lane = threadIdx.x & 63;
    const int wid = (blockIdx.x * blockDim.x + threadIdx.x) >> 6;
    if (wid >= n_nodes) return;
    const int e0 = __builtin_amdgcn_readfirstlane(row_ptr[wid]);
    const int e1 = __builtin_amdgcn_readfirstlane(row_ptr[wid + 1]);
    float2 accA = {0.f, 0.f}, accB = {0.f, 0.f};
    int e = e0;
    for (; e + 4 <= e1; e += 4) {
        int2 p0 = csr_edge[e + 0];
        int2 p1 = csr_edge[e + 1];
        int2 p2 = csr_edge[e + 2];
        int2 p3 = csr_edge[e + 3];
        unsigned int u0 = xb[(long)p0.x * 64 + lane];
        unsigned int u1 = xb[(long)p1.x * 64 + lane];
        unsigned int u2 = xb[(long)p2.x * 64 + lane];
        unsigned int u3 = xb[(long)p3.x * 64 + lane];
        float a0 = __int_as_float(p0.y), a1 = __int_as_float(p1.y);
        float a2 = __int_as_float(p2.y), a3 = __int_as_float(p3.y);
        accA.x = fmaf(a0, bf_lo(u0), accA.x); accA.y = fmaf(a0, bf_hi(u0), accA.y);
        accB.x = fmaf(a1, bf_lo(u1), accB.x); accB.y = fmaf(a1, bf_hi(u1), accB.y);
        accA.x = fmaf(a2, bf_lo(u2), accA.x); accA.y = fmaf(a2, bf_hi(u2), accA.y);
        accB.x = fmaf(a3, bf_lo(u3), accB.x); accB.y = fmaf(a3, bf_hi(u3), accB.y);
    }
    for (; e < e1; ++e) {
        int2 p = csr_edge[e];
        unsigned int u = xb[(long)p.x * 64 + lane];
        float a = __int_as_float(p.y);
        accA.x = fmaf(a, bf_lo(u), accA.x); accA.y = fmaf(a, bf_hi(u), accA.y);
    }
    accA.x += accB.x; accA.y += accB.y;
    reinterpret_cast<float2*>(hagg + (long)wid * 128)[lane] = accA;
}

// ---------------------------------------------------------------------------
// aggregation D=64 (bf16 table): wave handles 2 edges at once (32 lanes each)
// ---------------------------------------------------------------------------
__global__ void agg64_bf_kernel(const unsigned int* __restrict__ xb,    // row = 32 uints
                                const int* __restrict__ row_ptr,
                                const int2* __restrict__ csr_edge,
                                float* __restrict__ hagg, int n_nodes) {
    const int lane = threadIdx.x & 63;
    const int half = lane >> 5;
    const int l = lane & 31;
    const int wid = (blockIdx.x * blockDim.x + threadIdx.x) >> 6;
    if (wid >= n_nodes) return;
    const int e0 = __builtin_amdgcn_readfirstlane(row_ptr[wid]);
    const int e1 = __builtin_amdgcn_readfirstlane(row_ptr[wid + 1]);
    float2 accA = {0.f, 0.f}, accB = {0.f, 0.f};
    int e = e0;
    for (; e + 4 <= e1; e += 4) {
        int2 pA = csr_edge[e + half];
        int2 pB = csr_edge[e + 2 + half];
        unsigned int uA = xb[(long)pA.x * 32 + l];
        unsigned int uB = xb[(long)pB.x * 32 + l];
        float aA = __int_as_float(pA.y), aB = __int_as_float(pB.y);
        accA.x = fmaf(aA, bf_lo(uA), accA.x); accA.y = fmaf(aA, bf_hi(uA), accA.y);
        accB.x = fmaf(aB, bf_lo(uB), accB.x); accB.y = fmaf(aB, bf_hi(uB), accB.y);
    }
    if (e + 2 <= e1) {
        int2 p = csr_edge[e + half];
        unsigned int u = xb[(long)p.x * 32 + l];
        float a = __int_as_float(p.y);
        accA.x = fmaf(a, bf_lo(u), accA.x); accA.y = fmaf(a, bf_hi(u), accA.y);
        e += 2;
    }
    if (e < e1 && half == 0) {
        int2 p = csr_edge[e];
        unsigned int u = xb[(long)p.x * 32 + l];
        float a = __int_as_float(p.y);
        accA.x = fmaf(a, bf_lo(u), accA.x); accA.y = fmaf(a, bf_hi(u), accA.y);
    }
    accA.x += accB.x; accA.y += accB.y;
    accA.x += __shfl_xor(accA.x, 32);
    accA.y += __shfl_xor(accA.y, 32);
    if (half == 0) {
        reinterpret_cast<float2*>(hagg + (long)wid * 64)[l] = accA;
    }
}

// ---------------------------------------------------------------------------
// fp32-table fallback aggregation (R2-proven), used when ws too small for xb
// ---------------------------------------------------------------------------
template <int D>
__global__ void agg_f32_kernel(const float* __restrict__ xin, long xstride,
                               const int* __restrict__ row_ptr,
                               const int2* __restrict__ csr_edge,
                               float* __restrict__ hagg, int n_nodes) {
    const int lane = threadIdx.x & 63;
    const int wid = (blockIdx.x * blockDim.x + threadIdx.x) >> 6;
    if (wid >= n_nodes) return;
    const int e0 = row_ptr[wid], e1 = row_ptr[wid + 1];
    if (D == 128) {
        float2 accA = {0.f, 0.f}, accB = {0.f, 0.f};
        int e = e0;
        for (; e + 4 <= e1; e += 4) {
            int2 p0 = csr_edge[e + 0];
            int2 p1 = csr_edge[e + 1];
            int2 p2 = csr_edge[e + 2];
            int2 p3 = csr_edge[e + 3];
            float2 x0 = reinterpret_cast<const float2*>(xin + (long)p0.x * xstride)[lane];
            float2 x1 = reinterpret_cast<const float2*>(xin + (long)p1.x * xstride)[lane];
            float2 x2 = reinterpret_cast<const float2*>(xin + (long)p2.x * xstride)[lane];
            float2 x3 = reinterpret_cast<const float2*>(xin + (long)p3.x * xstride)[lane];
            float a0 = __int_as_float(p0.y), a1 = __int_as_float(p1.y);
            float a2 = __int_as_float(p2.y), a3 = __int_as_float(p3.y);
            accA.x = fmaf(a0, x0.x, accA.x); accA.y = fmaf(a0, x0.y, accA.y);
            accB.x = fmaf(a1, x1.x, accB.x); accB.y = fmaf(a1, x1.y, accB.y);
            accA.x = fmaf(a2, x2.x, accA.x); accA.y = fmaf(a2, x2.y, accA.y);
            accB.x = fmaf(a3, x3.x, accB.x); accB.y = fmaf(a3, x3.y, accB.y);
        }
        for (; e < e1; ++e) {
            int2 p = csr_edge[e];
            float2 xv = reinterpret_cast<const float2*>(xin + (long)p.x * xstride)[lane];
            float a = __int_as_float(p.y);
            accA.x = fmaf(a, xv.x, accA.x); accA.y = fmaf(a, xv.y, accA.y);
        }
        accA.x += accB.x; accA.y += accB.y;
        reinterpret_cast<float2*>(hagg + (long)wid * 128)[lane] = accA;
    } else {  // D == 64
        float accA = 0.f, accB = 0.f;
        int e = e0;
        for (; e + 4 <= e1; e += 4) {
            int2 p0 = csr_edge[e + 0];
            int2 p1 = csr_edge[e + 1];
            int2 p2 = csr_edge[e + 2];
            int2 p3 = csr_edge[e + 3];
            float x0 = xin[(long)p0.x * xstride + lane];
            float x1 = xin[(long)p1.x * xstride + lane];
            float x2 = xin[(long)p2.x * xstride + lane];
            float x3 = xin[(long)p3.x * xstride + lane];
            accA = fmaf(__int_as_float(p0.y), x0, accA);
            accB = fmaf(__int_as_float(p1.y), x1, accB);
            accA = fmaf(__int_as_float(p2.y), x2, accA);
            accB = fmaf(__int_as_float(p3.y), x3, accB);
        }
        for (; e < e1; ++e) {
            int2 p = csr_edge[e];
            accA = fmaf(__int_as_float(p.y), xin[(long)p.x * xstride + lane], accA);
        }
        hagg[(long)wid * 64 + lane] = accA + accB;
    }
}

// ---------------------------------------------------------------------------
// bi-interaction MLP: out[v,o] = lrelu((x+h)@W1+b1) + lrelu((x*h)@W2+b2)
// optional bf16 copy of the output row (next layer's gather table).
// ---------------------------------------------------------------------------
template <int IN, int OUT, int NT>
__global__ void mlp_kernel(const float* __restrict__ xin, long xstride,
                           const float* __restrict__ hagg,
                           const float* __restrict__ W1, const float* __restrict__ b1,
                           const float* __restrict__ W2, const float* __restrict__ b2,
                           float* __restrict__ out, long ostride,
                           unsigned short* __restrict__ xb_next, int n_nodes) {
    constexpr int SLOTS = 256 / OUT;
    constexpr int NPB = SLOTS * NT;
    __shared__ float s_xp[NPB][IN + 4];
    __shared__ float s_xm[NPB][IN + 4];
    const int t = threadIdx.x;
    const int o = t % OUT;
    const int slot = t / OUT;
    const int node0 = blockIdx.x * NPB;

    // stage (x+h) and (x*h), float4 granularity
    for (int idx = t; idx < NPB * (IN / 4); idx += 256) {
        int n = idx / (IN / 4), c = idx % (IN / 4);
        int k = c * 4;
        int v = node0 + n;
        float4 xv = {0.f, 0.f, 0.f, 0.f}, hv = {0.f, 0.f, 0.f, 0.f};
        if (v < n_nodes) {
            xv = *reinterpret_cast<const float4*>(xin + (long)v * xstride + k);
            hv = *reinterpret_cast<const float4*>(hagg + (long)v * IN + k);
        }
        *reinterpret_cast<float4*>(&s_xp[n][k]) =
            make_float4(xv.x + hv.x, xv.y + hv.y, xv.z + hv.z, xv.w + hv.w);
        *reinterpret_cast<float4*>(&s_xm[n][k]) =
            make_float4(xv.x * hv.x, xv.y * hv.y, xv.z * hv.z, xv.w * hv.w);
    }
    __syncthreads();

    float acc1[NT], acc2[NT];
#pragma unroll
    for (int j = 0; j < NT; ++j) { acc1[j] = 0.f; acc2[j] = 0.f; }

    for (int k = 0; k < IN; k += 4) {
        float w10 = W1[(k + 0) * OUT + o], w11 = W1[(k + 1) * OUT + o];
        float w12 = W1[(k + 2) * OUT + o], w13 = W1[(k + 3) * OUT + o];
        float w20 = W2[(k + 0) * OUT + o], w21 = W2[(k + 1) * OUT + o];
        float w22 = W2[(k + 2) * OUT + o], w23 = W2[(k + 3) * OUT + o];
#pragma unroll
        for (int j = 0; j < NT; ++j) {
            int n = slot * NT + j;
            float4 xp = *reinterpret_cast<const float4*>(&s_xp[n][k]);
            float4 xm = *reinterpret_cast<const float4*>(&s_xm[n][k]);
            acc1[j] = fmaf(xp.x, w10, acc1[j]); acc1[j] = fmaf(xp.y, w11, acc1[j]);
            acc1[j] = fmaf(xp.z, w12, acc1[j]); acc1[j] = fmaf(xp.w, w13, acc1[j]);
            acc2[j] = fmaf(xm.x, w20, acc2[j]); acc2[j] = fmaf(xm.y, w21, acc2[j]);
            acc2[j] = fmaf(xm.z, w22, acc2[j]); acc2[j] = fmaf(xm.w, w23, acc2[j]);
        }
    }

    const float bb1 = b1[o], bb2 = b2[o];
#pragma unroll
    for (int j = 0; j < NT; ++j) {
        int v = node0 + slot * NT + j;
        if (v < n_nodes) {
            float r1 = acc1[j] + bb1;
            float r2 = acc2[j] + bb2;
            r1 = r1 >= 0.f ? r1 : LRELU_SLOPE * r1;
            r2 = r2 >= 0.f ? r2 : LRELU_SLOPE * r2;
            float r = r1 + r2;
            out[(long)v * ostride + o] = r;
            if (xb_next) xb_next[(long)v * OUT + o] = (unsigned short)f2bf_rne(r);
        }
    }
}

// ---------------------------------------------------------------------------
extern "C" void kernel_launch(void* const* d_in, const int* in_sizes, int n_in,
                              void* d_out, int out_size, void* d_ws, size_t ws_size,
                              hipStream_t stream) {
    const float* x    = (const float*)d_in[0];
    const int*   src  = (const int*)d_in[1];
    const int*   dst  = (const int*)d_in[2];
    const float* attn = (const float*)d_in[3];
    const float* W1_0 = (const float*)d_in[4];
    const float* b1_0 = (const float*)d_in[5];
    const float* W2_0 = (const float*)d_in[6];
    const float* b2_0 = (const float*)d_in[7];
    const float* W1_1 = (const float*)d_in[8];
    const float* b1_1 = (const float*)d_in[9];
    const float* W2_1 = (const float*)d_in[10];
    const float* b2_1 = (const float*)d_in[11];
    const float* W1_2 = (const float*)d_in[12];
    const float* b1_2 = (const float*)d_in[13];
    const float* W2_2 = (const float*)d_in[14];
    const float* b2_2 = (const float*)d_in[15];
    float* out = (float*)d_out;

    const int N = in_sizes[0] / 128;
    const int E = in_sizes[1];

    char* w = (char*)d_ws;
    size_t off = 0;
    auto alloc = [&](size_t bytes) -> void* {
        void* p = w + off;
        off += (bytes + 511) & ~(size_t)511;
        return p;
    };
    int*          counts   = (int*)alloc((size_t)N * 4);
    int*          row_ptr  = (int*)alloc((size_t)(N + 1) * 4);
    int*          partials = (int*)alloc((size_t)1024 * 4);
    int2*         csr_edge = (int2*)alloc((size_t)E * 8);
    float*        h_agg    = (float*)alloc((size_t)N * 128 * 4);
    size_t        base_off = off;
    unsigned int* xb       = (unsigned int*)alloc((size_t)N * 128 * 2);  // bf16 table

    // ws guard: bf16 fast path only if the full layout fits; else fp32 fallback.
    const bool use_bf16 = (off <= ws_size);
    (void)base_off;

    const int G = (N + 1023) / 1024;

    // ---- CSR build (reused by all 3 layers) ----
    hipMemsetAsync(counts, 0, (size_t)N * 4, stream);
    count_kernel<<<(E + 255) / 256, 256, 0, stream>>>(dst, counts, E);
    scan_blocks_kernel<<<G, 1024, 0, stream>>>(counts, row_ptr, partials, N);
    scan_partials_kernel<<<1, 1024, 0, stream>>>(partials, row_ptr, G, N);
    scan_add_kernel<<<(N + 255) / 256, 256, 0, stream>>>(row_ptr, partials, N);
    fill_kernel<<<(E + 255) / 256, 256, 0, stream>>>(src, dst, attn, row_ptr, counts,
                                                     csr_edge, E);

    // ---- out[:, 0:128] = x ----
    copy_x_kernel<<<(N * 32 + 255) / 256, 256, 0, stream>>>((const float4*)x, (float4*)out, N * 32);

    if (use_bf16) {
        cvt_kernel<<<(N * 64 + 255) / 256, 256, 0, stream>>>((const float2*)x, xb, N * 64);

        // layer 0: IN=128 OUT=128
        agg128_bf_kernel<<<(N + 3) / 4, 256, 0, stream>>>(xb, row_ptr, csr_edge, h_agg, N);
        mlp_kernel<128, 128, 4><<<(N + 7) / 8, 256, 0, stream>>>(x, 128, h_agg,
                                                                 W1_0, b1_0, W2_0, b2_0,
                                                                 out + 128, 352,
                                                                 (unsigned short*)xb, N);
        // layer 1: IN=128 OUT=64
        agg128_bf_kernel<<<(N + 3) / 4, 256, 0, stream>>>(xb, row_ptr, csr_edge, h_agg, N);
        mlp_kernel<128, 64, 4><<<(N + 15) / 16, 256, 0, stream>>>(out + 128, 352, h_agg,
                                                                  W1_1, b1_1, W2_1, b2_1,
                                                                  out + 256, 352,
                                                                  (unsigned short*)xb, N);
        // layer 2: IN=64 OUT=32
        agg64_bf_kernel<<<(N + 3) / 4, 256, 0, stream>>>(xb, row_ptr, csr_edge, h_agg, N);
        mlp_kernel<64, 32, 4><<<(N + 31) / 32, 256, 0, stream>>>(out + 256, 352, h_agg,
                                                                 W1_2, b1_2, W2_2, b2_2,
                                                                 out + 320, 352,
                                                                 (unsigned short*)nullptr, N);
    } else {
        // fp32 fallback (R2-proven path)
        agg_f32_kernel<128><<<(N + 3) / 4, 256, 0, stream>>>(x, 128, row_ptr, csr_edge, h_agg, N);
        mlp_kernel<128, 128, 4><<<(N + 7) / 8, 256, 0, stream>>>(x, 128, h_agg,
                                                                 W1_0, b1_0, W2_0, b2_0,
                                                                 out + 128, 352,
                                                                 (unsigned short*)nullptr, N);
        agg_f32_kernel<128><<<(N + 3) / 4, 256, 0, stream>>>(out + 128, 352, row_ptr, csr_edge, h_agg, N);
        mlp_kernel<128, 64, 4><<<(N + 15) / 16, 256, 0, stream>>>(out + 128, 352, h_agg,
                                                                  W1_1, b1_1, W2_1, b2_1,
                                                                  out + 256, 352,
                                                                  (unsigned short*)nullptr, N);
        agg_f32_kernel<64><<<(N + 3) / 4, 256, 0, stream>>>(out + 256, 352, row_ptr, csr_edge, h_agg, N);
        mlp_kernel<64, 32, 4><<<(N + 31) / 32, 256, 0, stream>>>(out + 256, 352, h_agg,
                                                                 W1_2, b1_2, W2_2, b2_2,
                                                                 out + 320, 352,
                                                                 (unsigned short*)nullptr, N);
    }
}